// Round 2
// baseline (452.204 us; speedup 1.0000x reference)
//
#include <hip/hip_runtime.h>
#include <math.h>

static __device__ __forceinline__ float lrelu(float x) { return x >= 0.f ? x : 0.2f * x; }

// ---------------- CSR build ----------------
__global__ __launch_bounds__(256) void count_deg(const int* __restrict__ dst, int E,
                                                 int* __restrict__ deg) {
    int i = blockIdx.x * 256 + threadIdx.x;
    if (i < E) atomicAdd(&deg[dst[i]], 1);
}

__global__ __launch_bounds__(256) void scan1(const int* __restrict__ deg, int N, int ntot,
                                             int* __restrict__ rowptr, int* __restrict__ csum) {
    __shared__ int s[256];
    int t = threadIdx.x;
    int i = blockIdx.x * 256 + t;
    int v = (i < N) ? deg[i] : 0;
    s[t] = v;
    __syncthreads();
    #pragma unroll
    for (int off = 1; off < 256; off <<= 1) {
        int add = (t >= off) ? s[t - off] : 0;
        __syncthreads();
        s[t] += add;
        __syncthreads();
    }
    if (i < ntot) rowptr[i] = s[t] - v;   // exclusive within chunk
    if (t == 255) csum[blockIdx.x] = s[255];
}

__global__ __launch_bounds__(256) void scan2(const int* __restrict__ csum,
                                             int* __restrict__ coff, int nch) {
    __shared__ int s[256];
    int t = threadIdx.x;
    int v = (t < nch) ? csum[t] : 0;
    s[t] = v;
    __syncthreads();
    #pragma unroll
    for (int off = 1; off < 256; off <<= 1) {
        int add = (t >= off) ? s[t - off] : 0;
        __syncthreads();
        s[t] += add;
        __syncthreads();
    }
    coff[t] = s[t] - v;                   // exclusive chunk offsets
}

__global__ __launch_bounds__(256) void scan3(int* __restrict__ rowptr,
                                             const int* __restrict__ coff, int ntot) {
    int i = blockIdx.x * 256 + threadIdx.x;
    if (i < ntot) rowptr[i] += coff[blockIdx.x];
}

__global__ __launch_bounds__(256) void fill_csr(const int* __restrict__ src,
                                                const int* __restrict__ dst, int E,
                                                const int* __restrict__ rowptr,
                                                int* __restrict__ cursor,
                                                int* __restrict__ colidx) {
    int i = blockIdx.x * 256 + threadIdx.x;
    if (i < E) {
        int d = dst[i];
        int p = atomicAdd(&cursor[d], 1);
        colidx[rowptr[d] + p] = src[i];
    }
}

// ---------------- GEMM: h[r,128] = x[r,128] @ W[128,128] ----------------
// block = 256 threads, 64 rows per block, 8 rows x 4 cols per thread.
// LDS: x tile 32KB + W k-chunk 32KB = 64KB.
__global__ __launch_bounds__(256) void gemm128(const float* __restrict__ x,
                                               const float* __restrict__ W,
                                               float* __restrict__ h, int nrows) {
    __shared__ float xs[64 * 128];
    __shared__ float ws[64 * 128];
    const int t = threadIdx.x;
    const int row0 = blockIdx.x * 64;

    {   // stage x tile
        const float4* x4 = (const float4*)x;
        float4* xs4 = (float4*)xs;
        #pragma unroll
        for (int i = 0; i < 8; ++i) {
            int idx = t + i * 256;                 // 0..2047, row = idx>>5, colq = idx&31
            int r = row0 + (idx >> 5);
            float4 v = make_float4(0.f, 0.f, 0.f, 0.f);
            if (r < nrows) v = x4[(size_t)row0 * 32 + idx];
            xs4[idx] = v;
        }
    }

    const int col0 = (t & 31) * 4;
    const int r0 = (t >> 5) * 8;
    float acc[8][4];
    #pragma unroll
    for (int j = 0; j < 8; ++j)
        #pragma unroll
        for (int c = 0; c < 4; ++c) acc[j][c] = 0.f;

    for (int kc = 0; kc < 2; ++kc) {
        {   // stage W rows [kc*64, kc*64+64)
            const float4* W4 = (const float4*)(W + kc * 64 * 128);
            float4* ws4 = (float4*)ws;
            #pragma unroll
            for (int i = 0; i < 8; ++i) ws4[t + i * 256] = W4[t + i * 256];
        }
        __syncthreads();
        #pragma unroll 4
        for (int k = 0; k < 64; ++k) {
            float4 wv = *(const float4*)&ws[k * 128 + col0];
            #pragma unroll
            for (int j = 0; j < 8; ++j) {
                float xv = xs[(r0 + j) * 128 + kc * 64 + k];
                acc[j][0] = fmaf(xv, wv.x, acc[j][0]);
                acc[j][1] = fmaf(xv, wv.y, acc[j][1]);
                acc[j][2] = fmaf(xv, wv.z, acc[j][2]);
                acc[j][3] = fmaf(xv, wv.w, acc[j][3]);
            }
        }
        __syncthreads();
    }

    #pragma unroll
    for (int j = 0; j < 8; ++j) {
        int r = row0 + r0 + j;
        if (r < nrows)
            *(float4*)&h[(size_t)r * 128 + col0] =
                make_float4(acc[j][0], acc[j][1], acc[j][2], acc[j][3]);
    }
}

// ---------------- alpha_s / alpha_d: per (node, head) dot of 32 ----------------
__global__ __launch_bounds__(256) void alpha_kernel(const float* __restrict__ h,
                                                    const float* __restrict__ a_src,
                                                    const float* __restrict__ a_dst,
                                                    float* __restrict__ as_,
                                                    float* __restrict__ ad_, int n) {
    int idx = blockIdx.x * 256 + threadIdx.x;
    if (idx >= n * 4) return;
    int node = idx >> 2, hd = idx & 3;
    const float4* hp = (const float4*)(h + (size_t)node * 128 + hd * 32);
    const float4* s4 = (const float4*)(a_src + hd * 32);
    const float4* d4 = (const float4*)(a_dst + hd * 32);
    float s = 0.f, d = 0.f;
    #pragma unroll
    for (int c = 0; c < 8; ++c) {
        float4 v = hp[c], a = s4[c], b = d4[c];
        s += v.x * a.x + v.y * a.y + v.z * a.z + v.w * a.w;
        d += v.x * b.x + v.y * b.y + v.z * b.z + v.w * b.w;
    }
    as_[idx] = s;
    ad_[idx] = d;
}

// ---------------- aggregation: one wave per dst node ----------------
// Softmax shift-invariance: alpha = exp(e)/sum(exp(e)) exactly equals the
// reference's max-subtracted form (|e| <~ 5, fp32-safe). Self-loop handled
// explicitly (reference appends one per node).
__global__ __launch_bounds__(256) void aggregate(const float* __restrict__ h,
                                                 const float* __restrict__ as_,
                                                 const float* __restrict__ ad_,
                                                 const int* __restrict__ rowptr,
                                                 const int* __restrict__ colidx,
                                                 const float* __restrict__ bias,
                                                 float* __restrict__ out, int n, int do_elu) {
    int node = blockIdx.x * 4 + (threadIdx.x >> 6);
    if (node >= n) return;
    int lane = threadIdx.x & 63;
    int hd = lane >> 4;          // head of this lane's 2 columns
    int k = lane * 2;
    float adn = ad_[node * 4 + hd];
    float accx = 0.f, accy = 0.f, denom = 0.f;

    {   // self loop
        float wgt = __expf(lrelu(as_[node * 4 + hd] + adn));
        float2 hv = *(const float2*)&h[(size_t)node * 128 + k];
        accx = fmaf(wgt, hv.x, accx);
        accy = fmaf(wgt, hv.y, accy);
        denom += wgt;
    }
    int beg = rowptr[node], end = rowptr[node + 1];
    for (int j = beg; j < end; ++j) {
        int src = colidx[j];
        float wgt = __expf(lrelu(as_[src * 4 + hd] + adn));
        float2 hv = *(const float2*)&h[(size_t)src * 128 + k];
        accx = fmaf(wgt, hv.x, accx);
        accy = fmaf(wgt, hv.y, accy);
        denom += wgt;
    }
    float inv = 1.f / (denom + 1e-16f);
    float o0 = fmaf(accx, inv, bias[k]);
    float o1 = fmaf(accy, inv, bias[k + 1]);
    if (do_elu) {
        o0 = o0 > 0.f ? o0 : (__expf(o0) - 1.f);
        o1 = o1 > 0.f ? o1 : (__expf(o1) - 1.f);
    }
    *(float2*)&out[(size_t)node * 128 + k] = make_float2(o0, o1);
}

extern "C" void kernel_launch(void* const* d_in, const int* in_sizes, int n_in,
                              void* d_out, int out_size, void* d_ws, size_t ws_size,
                              hipStream_t stream) {
    const float* x   = (const float*)d_in[0];
    const int*   ei  = (const int*)d_in[1];
    const float* W1  = (const float*)d_in[2];
    const float* a1s = (const float*)d_in[3];
    const float* a1d = (const float*)d_in[4];
    const float* b1  = (const float*)d_in[5];
    const float* W2  = (const float*)d_in[6];
    const float* a2s = (const float*)d_in[7];
    const float* a2d = (const float*)d_in[8];
    const float* b2  = (const float*)d_in[9];
    float* out = (float*)d_out;

    const int N = in_sizes[0] / 128;
    const int E = in_sizes[1] / 2;
    const int* esrc = ei;
    const int* edst = ei + E;

    char* w = (char*)d_ws;
    float* h    = (float*)w; w += (size_t)N * 128 * 4;
    float* out1 = (float*)w; w += (size_t)N * 128 * 4;
    float* as_  = (float*)w; w += (size_t)N * 4 * 4;
    float* ad_  = (float*)w; w += (size_t)N * 4 * 4;
    int* deg    = (int*)w;   w += (size_t)N * 4;
    int* rowptr = (int*)w;   w += (size_t)(N + 1) * 4;
    int* cursor = (int*)w;   w += (size_t)N * 4;
    int* colidx = (int*)w;   w += (size_t)E * 4;
    int* csum   = (int*)w;   w += 256 * 4;
    int* coff   = (int*)w;   w += 256 * 4;

    hipMemsetAsync(deg, 0, (size_t)N * 4, stream);
    hipMemsetAsync(cursor, 0, (size_t)N * 4, stream);

    const int eb = (E + 255) / 256;
    const int ntot = N + 1;
    const int nch = (ntot + 255) / 256;

    count_deg<<<eb, 256, 0, stream>>>(edst, E, deg);
    scan1<<<nch, 256, 0, stream>>>(deg, N, ntot, rowptr, csum);
    scan2<<<1, 256, 0, stream>>>(csum, coff, nch);
    scan3<<<nch, 256, 0, stream>>>(rowptr, coff, ntot);
    fill_csr<<<eb, 256, 0, stream>>>(esrc, edst, E, rowptr, cursor, colidx);

    const int gb = (N + 63) / 64;
    const int ab = (N * 4 + 255) / 256;
    const int nb = (N + 3) / 4;

    // layer 1
    gemm128<<<gb, 256, 0, stream>>>(x, W1, h, N);
    alpha_kernel<<<ab, 256, 0, stream>>>(h, a1s, a1d, as_, ad_, N);
    aggregate<<<nb, 256, 0, stream>>>(h, as_, ad_, rowptr, colidx, b1, out1, N, 1);

    // layer 2
    gemm128<<<gb, 256, 0, stream>>>(out1, W2, h, N);
    alpha_kernel<<<ab, 256, 0, stream>>>(h, a2s, a2d, as_, ad_, N);
    aggregate<<<nb, 256, 0, stream>>>(h, as_, ad_, rowptr, colidx, b2, out, N, 0);
}

// Round 3
// 399.206 us; speedup vs baseline: 1.1328x; 1.1328x over previous
//
#include <hip/hip_runtime.h>
#include <math.h>

static __device__ __forceinline__ float lrelu(float x) { return x >= 0.f ? x : 0.2f * x; }

// ---------------- CSR build ----------------
__global__ __launch_bounds__(256) void count_deg(const int* __restrict__ dst, int E,
                                                 int* __restrict__ deg) {
    int i = blockIdx.x * 256 + threadIdx.x;
    if (i < E) atomicAdd(&deg[dst[i]], 1);
}

__global__ __launch_bounds__(256) void scan1(const int* __restrict__ deg, int N, int ntot,
                                             int* __restrict__ rowptr, int* __restrict__ csum) {
    __shared__ int s[256];
    int t = threadIdx.x;
    int i = blockIdx.x * 256 + t;
    int v = (i < N) ? deg[i] : 0;
    s[t] = v;
    __syncthreads();
    #pragma unroll
    for (int off = 1; off < 256; off <<= 1) {
        int add = (t >= off) ? s[t - off] : 0;
        __syncthreads();
        s[t] += add;
        __syncthreads();
    }
    if (i < ntot) rowptr[i] = s[t] - v;   // exclusive within chunk
    if (t == 255) csum[blockIdx.x] = s[255];
}

__global__ __launch_bounds__(256) void scan2(const int* __restrict__ csum,
                                             int* __restrict__ coff, int nch) {
    __shared__ int s[256];
    int t = threadIdx.x;
    int v = (t < nch) ? csum[t] : 0;
    s[t] = v;
    __syncthreads();
    #pragma unroll
    for (int off = 1; off < 256; off <<= 1) {
        int add = (t >= off) ? s[t - off] : 0;
        __syncthreads();
        s[t] += add;
        __syncthreads();
    }
    coff[t] = s[t] - v;                   // exclusive chunk offsets
}

__global__ __launch_bounds__(256) void scan3(int* __restrict__ rowptr,
                                             const int* __restrict__ coff, int ntot) {
    int i = blockIdx.x * 256 + threadIdx.x;
    if (i < ntot) rowptr[i] += coff[blockIdx.x];
}

__global__ __launch_bounds__(256) void fill_csr(const int* __restrict__ src,
                                                const int* __restrict__ dst, int E,
                                                const int* __restrict__ rowptr,
                                                int* __restrict__ cursor,
                                                int* __restrict__ colidx) {
    int i = blockIdx.x * 256 + threadIdx.x;
    if (i < E) {
        int d = dst[i];
        int p = atomicAdd(&cursor[d], 1);
        colidx[rowptr[d] + p] = src[i];
    }
}

// ---------------- GEMM: h[r,128] = x[r,128] @ W[128,128] ----------------
// block = 256 threads, 64 rows per block, 8 rows x 4 cols per thread.
// Inner loop processes 4 k's per step: xs read as float4 along k (broadcast
// across the 32 lanes of a row-group -> conflict-free), ws read as float4.
__global__ __launch_bounds__(256) void gemm128(const float* __restrict__ x,
                                               const float* __restrict__ W,
                                               float* __restrict__ h, int nrows) {
    __shared__ float xs[64 * 128];
    __shared__ float ws[64 * 128];
    const int t = threadIdx.x;
    const int row0 = blockIdx.x * 64;

    {   // stage x tile
        const float4* x4 = (const float4*)x;
        float4* xs4 = (float4*)xs;
        #pragma unroll
        for (int i = 0; i < 8; ++i) {
            int idx = t + i * 256;                 // 0..2047, row = idx>>5, colq = idx&31
            int r = row0 + (idx >> 5);
            float4 v = make_float4(0.f, 0.f, 0.f, 0.f);
            if (r < nrows) v = x4[(size_t)row0 * 32 + idx];
            xs4[idx] = v;
        }
    }

    const int col0 = (t & 31) * 4;
    const int r0 = (t >> 5) * 8;
    float acc[8][4];
    #pragma unroll
    for (int j = 0; j < 8; ++j)
        #pragma unroll
        for (int c = 0; c < 4; ++c) acc[j][c] = 0.f;

    for (int kc = 0; kc < 2; ++kc) {
        {   // stage W rows [kc*64, kc*64+64)
            const float4* W4 = (const float4*)(W + kc * 64 * 128);
            float4* ws4 = (float4*)ws;
            #pragma unroll
            for (int i = 0; i < 8; ++i) ws4[t + i * 256] = W4[t + i * 256];
        }
        __syncthreads();
        #pragma unroll 2
        for (int k4 = 0; k4 < 64; k4 += 4) {
            float4 xv[8];
            #pragma unroll
            for (int j = 0; j < 8; ++j)
                xv[j] = *(const float4*)&xs[(r0 + j) * 128 + kc * 64 + k4];
            #pragma unroll
            for (int kk = 0; kk < 4; ++kk) {
                float4 wv = *(const float4*)&ws[(k4 + kk) * 128 + col0];
                #pragma unroll
                for (int j = 0; j < 8; ++j) {
                    float xvk = (kk == 0) ? xv[j].x : (kk == 1) ? xv[j].y
                              : (kk == 2) ? xv[j].z : xv[j].w;
                    acc[j][0] = fmaf(xvk, wv.x, acc[j][0]);
                    acc[j][1] = fmaf(xvk, wv.y, acc[j][1]);
                    acc[j][2] = fmaf(xvk, wv.z, acc[j][2]);
                    acc[j][3] = fmaf(xvk, wv.w, acc[j][3]);
                }
            }
        }
        __syncthreads();
    }

    #pragma unroll
    for (int j = 0; j < 8; ++j) {
        int r = row0 + r0 + j;
        if (r < nrows)
            *(float4*)&h[(size_t)r * 128 + col0] =
                make_float4(acc[j][0], acc[j][1], acc[j][2], acc[j][3]);
    }
}

// ---------------- alpha_s / alpha_d: per (node, head) dot of 32 ----------------
__global__ __launch_bounds__(256) void alpha_kernel(const float* __restrict__ h,
                                                    const float* __restrict__ a_src,
                                                    const float* __restrict__ a_dst,
                                                    float* __restrict__ as_,
                                                    float* __restrict__ ad_, int n) {
    int idx = blockIdx.x * 256 + threadIdx.x;
    if (idx >= n * 4) return;
    int node = idx >> 2, hd = idx & 3;
    const float4* hp = (const float4*)(h + (size_t)node * 128 + hd * 32);
    const float4* s4 = (const float4*)(a_src + hd * 32);
    const float4* d4 = (const float4*)(a_dst + hd * 32);
    float s = 0.f, d = 0.f;
    #pragma unroll
    for (int c = 0; c < 8; ++c) {
        float4 v = hp[c], a = s4[c], b = d4[c];
        s += v.x * a.x + v.y * a.y + v.z * a.z + v.w * a.w;
        d += v.x * b.x + v.y * b.y + v.z * b.z + v.w * b.w;
    }
    as_[idx] = s;
    ad_[idx] = d;
}

// ---------------- aggregation: one wave per dst node ----------------
// 4-way unrolled edge loop: 4 independent colidx->(as_,h-row) load chains in
// flight per iteration (memory-level parallelism; the round-2 profile showed
// latency-bound behavior at 39% of achievable HBM BW).
// Softmax shift-invariance: alpha = exp(e)/sum(exp(e)) equals the reference's
// max-subtracted form (|e| <~ 5, fp32-safe). Self-loop handled explicitly.
__global__ __launch_bounds__(256) void aggregate(const float* __restrict__ h,
                                                 const float* __restrict__ as_,
                                                 const float* __restrict__ ad_,
                                                 const int* __restrict__ rowptr,
                                                 const int* __restrict__ colidx,
                                                 const float* __restrict__ bias,
                                                 float* __restrict__ out, int n, int do_elu) {
    int node = blockIdx.x * 4 + (threadIdx.x >> 6);
    if (node >= n) return;
    int lane = threadIdx.x & 63;
    int hd = lane >> 4;          // head of this lane's 2 columns
    int k = lane * 2;
    float adn = ad_[node * 4 + hd];
    float accx = 0.f, accy = 0.f, denom = 0.f;

    {   // self loop
        float wgt = __expf(lrelu(as_[node * 4 + hd] + adn));
        float2 hv = *(const float2*)&h[(size_t)node * 128 + k];
        accx = fmaf(wgt, hv.x, accx);
        accy = fmaf(wgt, hv.y, accy);
        denom += wgt;
    }
    const int beg = rowptr[node], end = rowptr[node + 1];
    int j = beg;
    for (; j + 4 <= end; j += 4) {
        int s0 = colidx[j];
        int s1 = colidx[j + 1];
        int s2 = colidx[j + 2];
        int s3 = colidx[j + 3];
        float a0 = as_[s0 * 4 + hd];
        float a1 = as_[s1 * 4 + hd];
        float a2 = as_[s2 * 4 + hd];
        float a3 = as_[s3 * 4 + hd];
        float2 h0 = *(const float2*)&h[(size_t)s0 * 128 + k];
        float2 h1 = *(const float2*)&h[(size_t)s1 * 128 + k];
        float2 h2 = *(const float2*)&h[(size_t)s2 * 128 + k];
        float2 h3 = *(const float2*)&h[(size_t)s3 * 128 + k];
        float w0 = __expf(lrelu(a0 + adn));
        float w1 = __expf(lrelu(a1 + adn));
        float w2 = __expf(lrelu(a2 + adn));
        float w3 = __expf(lrelu(a3 + adn));
        accx = fmaf(w0, h0.x, accx); accy = fmaf(w0, h0.y, accy);
        accx = fmaf(w1, h1.x, accx); accy = fmaf(w1, h1.y, accy);
        accx = fmaf(w2, h2.x, accx); accy = fmaf(w2, h2.y, accy);
        accx = fmaf(w3, h3.x, accx); accy = fmaf(w3, h3.y, accy);
        denom += (w0 + w1) + (w2 + w3);
    }
    for (; j < end; ++j) {
        int src = colidx[j];
        float wgt = __expf(lrelu(as_[src * 4 + hd] + adn));
        float2 hv = *(const float2*)&h[(size_t)src * 128 + k];
        accx = fmaf(wgt, hv.x, accx);
        accy = fmaf(wgt, hv.y, accy);
        denom += wgt;
    }
    float inv = 1.f / (denom + 1e-16f);
    float o0 = fmaf(accx, inv, bias[k]);
    float o1 = fmaf(accy, inv, bias[k + 1]);
    if (do_elu) {
        o0 = o0 > 0.f ? o0 : (__expf(o0) - 1.f);
        o1 = o1 > 0.f ? o1 : (__expf(o1) - 1.f);
    }
    *(float2*)&out[(size_t)node * 128 + k] = make_float2(o0, o1);
}

extern "C" void kernel_launch(void* const* d_in, const int* in_sizes, int n_in,
                              void* d_out, int out_size, void* d_ws, size_t ws_size,
                              hipStream_t stream) {
    const float* x   = (const float*)d_in[0];
    const int*   ei  = (const int*)d_in[1];
    const float* W1  = (const float*)d_in[2];
    const float* a1s = (const float*)d_in[3];
    const float* a1d = (const float*)d_in[4];
    const float* b1  = (const float*)d_in[5];
    const float* W2  = (const float*)d_in[6];
    const float* a2s = (const float*)d_in[7];
    const float* a2d = (const float*)d_in[8];
    const float* b2  = (const float*)d_in[9];
    float* out = (float*)d_out;

    const int N = in_sizes[0] / 128;
    const int E = in_sizes[1] / 2;
    const int* esrc = ei;
    const int* edst = ei + E;

    char* w = (char*)d_ws;
    float* h    = (float*)w; w += (size_t)N * 128 * 4;
    float* out1 = (float*)w; w += (size_t)N * 128 * 4;
    float* as_  = (float*)w; w += (size_t)N * 4 * 4;
    float* ad_  = (float*)w; w += (size_t)N * 4 * 4;
    int* deg    = (int*)w;   w += (size_t)N * 4;
    int* rowptr = (int*)w;   w += (size_t)(N + 1) * 4;
    int* cursor = (int*)w;   w += (size_t)N * 4;
    int* colidx = (int*)w;   w += (size_t)E * 4;
    int* csum   = (int*)w;   w += 256 * 4;
    int* coff   = (int*)w;   w += 256 * 4;

    hipMemsetAsync(deg, 0, (size_t)N * 4, stream);
    hipMemsetAsync(cursor, 0, (size_t)N * 4, stream);

    const int eb = (E + 255) / 256;
    const int ntot = N + 1;
    const int nch = (ntot + 255) / 256;

    count_deg<<<eb, 256, 0, stream>>>(edst, E, deg);
    scan1<<<nch, 256, 0, stream>>>(deg, N, ntot, rowptr, csum);
    scan2<<<1, 256, 0, stream>>>(csum, coff, nch);
    scan3<<<nch, 256, 0, stream>>>(rowptr, coff, ntot);
    fill_csr<<<eb, 256, 0, stream>>>(esrc, edst, E, rowptr, cursor, colidx);

    const int gb = (N + 63) / 64;
    const int ab = (N * 4 + 255) / 256;
    const int nb = (N + 3) / 4;

    // layer 1
    gemm128<<<gb, 256, 0, stream>>>(x, W1, h, N);
    alpha_kernel<<<ab, 256, 0, stream>>>(h, a1s, a1d, as_, ad_, N);
    aggregate<<<nb, 256, 0, stream>>>(h, as_, ad_, rowptr, colidx, b1, out1, N, 1);

    // layer 2
    gemm128<<<gb, 256, 0, stream>>>(out1, W2, h, N);
    alpha_kernel<<<ab, 256, 0, stream>>>(h, a2s, a2d, as_, ad_, N);
    aggregate<<<nb, 256, 0, stream>>>(h, as_, ad_, rowptr, colidx, b2, out, N, 0);
}

// Round 4
// 364.578 us; speedup vs baseline: 1.2403x; 1.0950x over previous
//
#include <hip/hip_runtime.h>
#include <math.h>
#include <stdint.h>

static __device__ __forceinline__ float lrelu(float x) { return x >= 0.f ? x : 0.2f * x; }

// round-to-nearest-even fp32 -> bf16 bits
static __device__ __forceinline__ uint32_t f2bf(float f) {
    uint32_t u = __float_as_uint(f);
    return (u + 0x7FFFu + ((u >> 16) & 1u)) >> 16;
}

// ---------------- CSR build ----------------
__global__ __launch_bounds__(256) void count_deg(const int* __restrict__ dst, int E,
                                                 int* __restrict__ deg) {
    int i = blockIdx.x * 256 + threadIdx.x;
    if (i < E) atomicAdd(&deg[dst[i]], 1);
}

__global__ __launch_bounds__(256) void scan1(const int* __restrict__ deg, int N, int ntot,
                                             int* __restrict__ rowptr, int* __restrict__ csum) {
    __shared__ int s[256];
    int t = threadIdx.x;
    int i = blockIdx.x * 256 + t;
    int v = (i < N) ? deg[i] : 0;
    s[t] = v;
    __syncthreads();
    #pragma unroll
    for (int off = 1; off < 256; off <<= 1) {
        int add = (t >= off) ? s[t - off] : 0;
        __syncthreads();
        s[t] += add;
        __syncthreads();
    }
    if (i < ntot) rowptr[i] = s[t] - v;   // exclusive within chunk
    if (t == 255) csum[blockIdx.x] = s[255];
}

__global__ __launch_bounds__(256) void scan2(const int* __restrict__ csum,
                                             int* __restrict__ coff, int nch) {
    __shared__ int s[256];
    int t = threadIdx.x;
    int v = (t < nch) ? csum[t] : 0;
    s[t] = v;
    __syncthreads();
    #pragma unroll
    for (int off = 1; off < 256; off <<= 1) {
        int add = (t >= off) ? s[t - off] : 0;
        __syncthreads();
        s[t] += add;
        __syncthreads();
    }
    coff[t] = s[t] - v;                   // exclusive chunk offsets
}

__global__ __launch_bounds__(256) void scan3(int* __restrict__ rowptr,
                                             const int* __restrict__ coff, int ntot) {
    int i = blockIdx.x * 256 + threadIdx.x;
    if (i < ntot) rowptr[i] += coff[blockIdx.x];
}

__global__ __launch_bounds__(256) void fill_csr(const int* __restrict__ src,
                                                const int* __restrict__ dst, int E,
                                                const int* __restrict__ rowptr,
                                                int* __restrict__ cursor,
                                                int* __restrict__ colidx) {
    int i = blockIdx.x * 256 + threadIdx.x;
    if (i < E) {
        int d = dst[i];
        int p = atomicAdd(&cursor[d], 1);
        colidx[rowptr[d] + p] = src[i];
    }
}

// ---------------- GEMM: h[r,128] = x[r,128] @ W[128,128] ----------------
// 128-row tile, BK=32 chunks, 256 threads as 16 rowgrp x 16 colgrp, 8x8 per
// thread. Per 4-k step: 16 ds_read_b128 for 256 FMAs (FMA-bound).
// Epilogue writes fp32 h (for alpha) and packed bf16 h (for aggregate).
__global__ __launch_bounds__(256) void gemm128(const float* __restrict__ x,
                                               const float* __restrict__ W,
                                               float* __restrict__ h,
                                               uint32_t* __restrict__ hbf,
                                               int nrows) {
    __shared__ float xs[128 * 32];
    __shared__ float ws[32 * 128];
    const int t = threadIdx.x;
    const int row0 = blockIdx.x * 128;
    const int rg = t >> 4;           // 0..15
    const int cg = t & 15;           // 0..15
    const int r0 = rg * 8;
    const int c0 = cg * 8;

    float acc[8][8];
    #pragma unroll
    for (int j = 0; j < 8; ++j)
        #pragma unroll
        for (int c = 0; c < 8; ++c) acc[j][c] = 0.f;

    const float4* x4 = (const float4*)x;
    const float4* W4 = (const float4*)W;
    float4* xs4 = (float4*)xs;
    float4* ws4 = (float4*)ws;

    for (int kc = 0; kc < 4; ++kc) {
        // stage x chunk [128 rows][32 k]
        #pragma unroll
        for (int i = 0; i < 4; ++i) {
            int idx = t + i * 256;           // 0..1023
            int r = idx >> 3, q = idx & 7;
            float4 v = make_float4(0.f, 0.f, 0.f, 0.f);
            if (row0 + r < nrows) v = x4[(size_t)(row0 + r) * 32 + kc * 8 + q];
            xs4[idx] = v;
        }
        // stage W chunk [32 k][128 cols]
        #pragma unroll
        for (int i = 0; i < 4; ++i) {
            int idx = t + i * 256;
            ws4[idx] = W4[kc * 1024 + idx];
        }
        __syncthreads();

        #pragma unroll 2
        for (int kk = 0; kk < 32; kk += 4) {
            float4 xv[8];
            #pragma unroll
            for (int j = 0; j < 8; ++j)
                xv[j] = xs4[(r0 + j) * 8 + (kk >> 2)];
            #pragma unroll
            for (int k2 = 0; k2 < 4; ++k2) {
                int k = kk + k2;
                float4 wv0 = ws4[k * 32 + cg * 2];
                float4 wv1 = ws4[k * 32 + cg * 2 + 1];
                #pragma unroll
                for (int j = 0; j < 8; ++j) {
                    float xk = (k2 == 0) ? xv[j].x : (k2 == 1) ? xv[j].y
                             : (k2 == 2) ? xv[j].z : xv[j].w;
                    acc[j][0] = fmaf(xk, wv0.x, acc[j][0]);
                    acc[j][1] = fmaf(xk, wv0.y, acc[j][1]);
                    acc[j][2] = fmaf(xk, wv0.z, acc[j][2]);
                    acc[j][3] = fmaf(xk, wv0.w, acc[j][3]);
                    acc[j][4] = fmaf(xk, wv1.x, acc[j][4]);
                    acc[j][5] = fmaf(xk, wv1.y, acc[j][5]);
                    acc[j][6] = fmaf(xk, wv1.z, acc[j][6]);
                    acc[j][7] = fmaf(xk, wv1.w, acc[j][7]);
                }
            }
        }
        __syncthreads();
    }

    #pragma unroll
    for (int j = 0; j < 8; ++j) {
        int r = row0 + r0 + j;
        if (r < nrows) {
            *(float4*)&h[(size_t)r * 128 + c0] =
                make_float4(acc[j][0], acc[j][1], acc[j][2], acc[j][3]);
            *(float4*)&h[(size_t)r * 128 + c0 + 4] =
                make_float4(acc[j][4], acc[j][5], acc[j][6], acc[j][7]);
            uint4 pk;
            pk.x = f2bf(acc[j][0]) | (f2bf(acc[j][1]) << 16);
            pk.y = f2bf(acc[j][2]) | (f2bf(acc[j][3]) << 16);
            pk.z = f2bf(acc[j][4]) | (f2bf(acc[j][5]) << 16);
            pk.w = f2bf(acc[j][6]) | (f2bf(acc[j][7]) << 16);
            *(uint4*)&hbf[(size_t)r * 64 + cg * 4] = pk;
        }
    }
}

// ---------------- alpha_s / alpha_d: per (node, head) dot of 32 ----------------
__global__ __launch_bounds__(256) void alpha_kernel(const float* __restrict__ h,
                                                    const float* __restrict__ a_src,
                                                    const float* __restrict__ a_dst,
                                                    float* __restrict__ as_,
                                                    float* __restrict__ ad_, int n) {
    int idx = blockIdx.x * 256 + threadIdx.x;
    if (idx >= n * 4) return;
    int node = idx >> 2, hd = idx & 3;
    const float4* hp = (const float4*)(h + (size_t)node * 128 + hd * 32);
    const float4* s4 = (const float4*)(a_src + hd * 32);
    const float4* d4 = (const float4*)(a_dst + hd * 32);
    float s = 0.f, d = 0.f;
    #pragma unroll
    for (int c = 0; c < 8; ++c) {
        float4 v = hp[c], a = s4[c], b = d4[c];
        s += v.x * a.x + v.y * a.y + v.z * a.z + v.w * a.w;
        d += v.x * b.x + v.y * b.y + v.z * b.z + v.w * b.w;
    }
    as_[idx] = s;
    ad_[idx] = d;
}

// ---------------- aggregation: one wave per dst node, bf16 h rows ----------------
// 8-way unrolled edge loop for memory-level parallelism; h rows are 256B bf16
// (halves the random-gather traffic vs fp32). Weights computed in fp32 from
// fp32 as_/ad_. Softmax shift-invariance: no max subtraction needed (|e|<~5).
__global__ __launch_bounds__(256) void aggregate(const uint32_t* __restrict__ hb,
                                                 const float* __restrict__ as_,
                                                 const float* __restrict__ ad_,
                                                 const int* __restrict__ rowptr,
                                                 const int* __restrict__ colidx,
                                                 const float* __restrict__ bias,
                                                 float* __restrict__ out, int n, int do_elu) {
    int node = blockIdx.x * 4 + (threadIdx.x >> 6);
    if (node >= n) return;
    int lane = threadIdx.x & 63;
    int hd = lane >> 4;          // head of this lane's 2 columns
    int k = lane * 2;
    float adn = ad_[node * 4 + hd];
    float accx = 0.f, accy = 0.f, denom = 0.f;

    {   // self loop
        float wgt = __expf(lrelu(as_[node * 4 + hd] + adn));
        uint32_t u = hb[(size_t)node * 64 + lane];
        accx = fmaf(wgt, __uint_as_float(u << 16), accx);
        accy = fmaf(wgt, __uint_as_float(u & 0xFFFF0000u), accy);
        denom += wgt;
    }
    const int beg = rowptr[node], end = rowptr[node + 1];
    int j = beg;
    for (; j + 8 <= end; j += 8) {
        int s0 = colidx[j],     s1 = colidx[j + 1];
        int s2 = colidx[j + 2], s3 = colidx[j + 3];
        int s4 = colidx[j + 4], s5 = colidx[j + 5];
        int s6 = colidx[j + 6], s7 = colidx[j + 7];
        float a0 = as_[s0 * 4 + hd], a1 = as_[s1 * 4 + hd];
        float a2 = as_[s2 * 4 + hd], a3 = as_[s3 * 4 + hd];
        float a4 = as_[s4 * 4 + hd], a5 = as_[s5 * 4 + hd];
        float a6 = as_[s6 * 4 + hd], a7 = as_[s7 * 4 + hd];
        uint32_t u0 = hb[(size_t)s0 * 64 + lane], u1 = hb[(size_t)s1 * 64 + lane];
        uint32_t u2 = hb[(size_t)s2 * 64 + lane], u3 = hb[(size_t)s3 * 64 + lane];
        uint32_t u4 = hb[(size_t)s4 * 64 + lane], u5 = hb[(size_t)s5 * 64 + lane];
        uint32_t u6 = hb[(size_t)s6 * 64 + lane], u7 = hb[(size_t)s7 * 64 + lane];
        float w0 = __expf(lrelu(a0 + adn)), w1 = __expf(lrelu(a1 + adn));
        float w2 = __expf(lrelu(a2 + adn)), w3 = __expf(lrelu(a3 + adn));
        float w4 = __expf(lrelu(a4 + adn)), w5 = __expf(lrelu(a5 + adn));
        float w6 = __expf(lrelu(a6 + adn)), w7 = __expf(lrelu(a7 + adn));
        accx = fmaf(w0, __uint_as_float(u0 << 16), accx);
        accy = fmaf(w0, __uint_as_float(u0 & 0xFFFF0000u), accy);
        accx = fmaf(w1, __uint_as_float(u1 << 16), accx);
        accy = fmaf(w1, __uint_as_float(u1 & 0xFFFF0000u), accy);
        accx = fmaf(w2, __uint_as_float(u2 << 16), accx);
        accy = fmaf(w2, __uint_as_float(u2 & 0xFFFF0000u), accy);
        accx = fmaf(w3, __uint_as_float(u3 << 16), accx);
        accy = fmaf(w3, __uint_as_float(u3 & 0xFFFF0000u), accy);
        accx = fmaf(w4, __uint_as_float(u4 << 16), accx);
        accy = fmaf(w4, __uint_as_float(u4 & 0xFFFF0000u), accy);
        accx = fmaf(w5, __uint_as_float(u5 << 16), accx);
        accy = fmaf(w5, __uint_as_float(u5 & 0xFFFF0000u), accy);
        accx = fmaf(w6, __uint_as_float(u6 << 16), accx);
        accy = fmaf(w6, __uint_as_float(u6 & 0xFFFF0000u), accy);
        accx = fmaf(w7, __uint_as_float(u7 << 16), accx);
        accy = fmaf(w7, __uint_as_float(u7 & 0xFFFF0000u), accy);
        denom += ((w0 + w1) + (w2 + w3)) + ((w4 + w5) + (w6 + w7));
    }
    for (; j < end; ++j) {
        int src = colidx[j];
        float wgt = __expf(lrelu(as_[src * 4 + hd] + adn));
        uint32_t u = hb[(size_t)src * 64 + lane];
        accx = fmaf(wgt, __uint_as_float(u << 16), accx);
        accy = fmaf(wgt, __uint_as_float(u & 0xFFFF0000u), accy);
        denom += wgt;
    }
    float inv = 1.f / (denom + 1e-16f);
    float o0 = fmaf(accx, inv, bias[k]);
    float o1 = fmaf(accy, inv, bias[k + 1]);
    if (do_elu) {
        o0 = o0 > 0.f ? o0 : (__expf(o0) - 1.f);
        o1 = o1 > 0.f ? o1 : (__expf(o1) - 1.f);
    }
    *(float2*)&out[(size_t)node * 128 + k] = make_float2(o0, o1);
}

extern "C" void kernel_launch(void* const* d_in, const int* in_sizes, int n_in,
                              void* d_out, int out_size, void* d_ws, size_t ws_size,
                              hipStream_t stream) {
    const float* x   = (const float*)d_in[0];
    const int*   ei  = (const int*)d_in[1];
    const float* W1  = (const float*)d_in[2];
    const float* a1s = (const float*)d_in[3];
    const float* a1d = (const float*)d_in[4];
    const float* b1  = (const float*)d_in[5];
    const float* W2  = (const float*)d_in[6];
    const float* a2s = (const float*)d_in[7];
    const float* a2d = (const float*)d_in[8];
    const float* b2  = (const float*)d_in[9];
    float* out = (float*)d_out;

    const int N = in_sizes[0] / 128;
    const int E = in_sizes[1] / 2;
    const int* esrc = ei;
    const int* edst = ei + E;

    char* w = (char*)d_ws;
    float*    h    = (float*)w;    w += (size_t)N * 128 * 4;
    uint32_t* hbf  = (uint32_t*)w; w += (size_t)N * 64 * 4;   // bf16-packed h
    float*    as_  = (float*)w;    w += (size_t)N * 4 * 4;
    float*    ad_  = (float*)w;    w += (size_t)N * 4 * 4;
    int* deg    = (int*)w;   w += (size_t)N * 4;
    int* rowptr = (int*)w;   w += (size_t)(N + 1) * 4;
    int* cursor = (int*)w;   w += (size_t)N * 4;
    int* colidx = (int*)w;   w += (size_t)E * 4;
    int* csum   = (int*)w;   w += 256 * 4;
    int* coff   = (int*)w;   w += 256 * 4;
    float* out1 = out;   // layer-1 output lives in d_out; consumed by layer-2
                         // gemm before the final aggregate overwrites d_out

    hipMemsetAsync(deg, 0, (size_t)N * 4, stream);
    hipMemsetAsync(cursor, 0, (size_t)N * 4, stream);

    const int eb = (E + 255) / 256;
    const int ntot = N + 1;
    const int nch = (ntot + 255) / 256;

    count_deg<<<eb, 256, 0, stream>>>(edst, E, deg);
    scan1<<<nch, 256, 0, stream>>>(deg, N, ntot, rowptr, csum);
    scan2<<<1, 256, 0, stream>>>(csum, coff, nch);
    scan3<<<nch, 256, 0, stream>>>(rowptr, coff, ntot);
    fill_csr<<<eb, 256, 0, stream>>>(esrc, edst, E, rowptr, cursor, colidx);

    const int gb = (N + 127) / 128;
    const int ab = (N * 4 + 255) / 256;
    const int nb = (N + 3) / 4;

    // layer 1
    gemm128<<<gb, 256, 0, stream>>>(x, W1, h, hbf, N);
    alpha_kernel<<<ab, 256, 0, stream>>>(h, a1s, a1d, as_, ad_, N);
    aggregate<<<nb, 256, 0, stream>>>(hbf, as_, ad_, rowptr, colidx, b1, out1, N, 1);

    // layer 2
    gemm128<<<gb, 256, 0, stream>>>(out1, W2, h, hbf, N);
    alpha_kernel<<<ab, 256, 0, stream>>>(h, a2s, a2d, as_, ad_, N);
    aggregate<<<nb, 256, 0, stream>>>(hbf, as_, ad_, rowptr, colidx, b2, out, N, 0);
}

// Round 5
// 300.149 us; speedup vs baseline: 1.5066x; 1.2147x over previous
//
#include <hip/hip_runtime.h>
#include <math.h>
#include <stdint.h>

static __device__ __forceinline__ float lrelu(float x) { return x >= 0.f ? x : 0.2f * x; }

// round-to-nearest-even fp32 -> bf16 bits
static __device__ __forceinline__ uint32_t f2bf(float f) {
    uint32_t u = __float_as_uint(f);
    return (u + 0x7FFFu + ((u >> 16) & 1u)) >> 16;
}

// ---------------- CSR build ----------------
// count + rank: the atomic's return value IS the within-node rank, so the
// fill pass needs no atomic at all.
__global__ __launch_bounds__(256) void count_rank(const int* __restrict__ dst, int E,
                                                  int* __restrict__ deg,
                                                  int* __restrict__ rank) {
    int i = blockIdx.x * 256 + threadIdx.x;
    if (i < E) rank[i] = atomicAdd(&deg[dst[i]], 1);
}

__global__ __launch_bounds__(256) void scan1(const int* __restrict__ deg, int N, int ntot,
                                             int* __restrict__ rowptr, int* __restrict__ csum) {
    __shared__ int s[256];
    int t = threadIdx.x;
    int i = blockIdx.x * 256 + t;
    int v = (i < N) ? deg[i] : 0;
    s[t] = v;
    __syncthreads();
    #pragma unroll
    for (int off = 1; off < 256; off <<= 1) {
        int add = (t >= off) ? s[t - off] : 0;
        __syncthreads();
        s[t] += add;
        __syncthreads();
    }
    if (i < ntot) rowptr[i] = s[t] - v;   // exclusive within chunk
    if (t == 255) csum[blockIdx.x] = s[255];
}

__global__ __launch_bounds__(256) void scan2(const int* __restrict__ csum,
                                             int* __restrict__ coff, int nch) {
    __shared__ int s[256];
    int t = threadIdx.x;
    int v = (t < nch) ? csum[t] : 0;
    s[t] = v;
    __syncthreads();
    #pragma unroll
    for (int off = 1; off < 256; off <<= 1) {
        int add = (t >= off) ? s[t - off] : 0;
        __syncthreads();
        s[t] += add;
        __syncthreads();
    }
    coff[t] = s[t] - v;                   // exclusive chunk offsets
}

__global__ __launch_bounds__(256) void scan3(int* __restrict__ rowptr,
                                             const int* __restrict__ coff, int ntot) {
    int i = blockIdx.x * 256 + threadIdx.x;
    if (i < ntot) rowptr[i] += coff[blockIdx.x];
}

__global__ __launch_bounds__(256) void fill_csr(const int* __restrict__ src,
                                                const int* __restrict__ dst,
                                                const int* __restrict__ rank, int E,
                                                const int* __restrict__ rowptr,
                                                int* __restrict__ colidx) {
    int i = blockIdx.x * 256 + threadIdx.x;
    if (i < E) colidx[rowptr[dst[i]] + rank[i]] = src[i];
}

// ---------------- fused GEMM + alpha ----------------
// h[r,128] = x[r,128] @ W[128,128]; writes bf16-packed h only, and computes
// as_[r,h] = h . a_src[h], ad_[r,h] = h . a_dst[h] from registers (fp32).
// 128-row tile, BK=32, 256 threads as 16 rowgrp x 16 colgrp, 8x8 per thread.
__global__ __launch_bounds__(256) void gemm_alpha(const float* __restrict__ x,
                                                  const float* __restrict__ W,
                                                  const float* __restrict__ a_src,
                                                  const float* __restrict__ a_dst,
                                                  uint32_t* __restrict__ hbf,
                                                  float* __restrict__ as_,
                                                  float* __restrict__ ad_,
                                                  int nrows) {
    __shared__ float xs[128 * 32];
    __shared__ float ws[32 * 128];
    const int t = threadIdx.x;
    const int row0 = blockIdx.x * 128;
    const int rg = t >> 4;           // 0..15
    const int cg = t & 15;           // 0..15
    const int r0 = rg * 8;
    const int c0 = cg * 8;

    float acc[8][8];
    #pragma unroll
    for (int j = 0; j < 8; ++j)
        #pragma unroll
        for (int c = 0; c < 8; ++c) acc[j][c] = 0.f;

    const float4* x4 = (const float4*)x;
    const float4* W4 = (const float4*)W;
    float4* xs4 = (float4*)xs;
    float4* ws4 = (float4*)ws;

    for (int kc = 0; kc < 4; ++kc) {
        #pragma unroll
        for (int i = 0; i < 4; ++i) {       // stage x chunk [128 rows][32 k]
            int idx = t + i * 256;           // 0..1023
            int r = idx >> 3, q = idx & 7;
            float4 v = make_float4(0.f, 0.f, 0.f, 0.f);
            if (row0 + r < nrows) v = x4[(size_t)(row0 + r) * 32 + kc * 8 + q];
            xs4[idx] = v;
        }
        #pragma unroll
        for (int i = 0; i < 4; ++i) {       // stage W chunk [32 k][128 cols]
            int idx = t + i * 256;
            ws4[idx] = W4[kc * 1024 + idx];
        }
        __syncthreads();

        #pragma unroll 2
        for (int kk = 0; kk < 32; kk += 4) {
            float4 xv[8];
            #pragma unroll
            for (int j = 0; j < 8; ++j)
                xv[j] = xs4[(r0 + j) * 8 + (kk >> 2)];
            #pragma unroll
            for (int k2 = 0; k2 < 4; ++k2) {
                int k = kk + k2;
                float4 wv0 = ws4[k * 32 + cg * 2];
                float4 wv1 = ws4[k * 32 + cg * 2 + 1];
                #pragma unroll
                for (int j = 0; j < 8; ++j) {
                    float xk = (k2 == 0) ? xv[j].x : (k2 == 1) ? xv[j].y
                             : (k2 == 2) ? xv[j].z : xv[j].w;
                    acc[j][0] = fmaf(xk, wv0.x, acc[j][0]);
                    acc[j][1] = fmaf(xk, wv0.y, acc[j][1]);
                    acc[j][2] = fmaf(xk, wv0.z, acc[j][2]);
                    acc[j][3] = fmaf(xk, wv0.w, acc[j][3]);
                    acc[j][4] = fmaf(xk, wv1.x, acc[j][4]);
                    acc[j][5] = fmaf(xk, wv1.y, acc[j][5]);
                    acc[j][6] = fmaf(xk, wv1.z, acc[j][6]);
                    acc[j][7] = fmaf(xk, wv1.w, acc[j][7]);
                }
            }
        }
        __syncthreads();
    }

    // epilogue: bf16 h + fused alpha dots.
    // cols c0..c0+7 all lie in head hd = cg>>2; a_src flat index == c_global.
    const int hd = cg >> 2;
    float asv[8], adv[8];
    #pragma unroll
    for (int cc = 0; cc < 8; ++cc) {
        asv[cc] = a_src[c0 + cc];
        adv[cc] = a_dst[c0 + cc];
    }
    #pragma unroll
    for (int j = 0; j < 8; ++j) {
        int r = row0 + r0 + j;
        float ps = 0.f, pd = 0.f;
        #pragma unroll
        for (int cc = 0; cc < 8; ++cc) {
            ps = fmaf(acc[j][cc], asv[cc], ps);
            pd = fmaf(acc[j][cc], adv[cc], pd);
        }
        // reduce across the 4 col-groups of this head (lane bits 0..1)
        ps += __shfl_xor(ps, 1); ps += __shfl_xor(ps, 2);
        pd += __shfl_xor(pd, 1); pd += __shfl_xor(pd, 2);
        if (r < nrows) {
            uint4 pk;
            pk.x = f2bf(acc[j][0]) | (f2bf(acc[j][1]) << 16);
            pk.y = f2bf(acc[j][2]) | (f2bf(acc[j][3]) << 16);
            pk.z = f2bf(acc[j][4]) | (f2bf(acc[j][5]) << 16);
            pk.w = f2bf(acc[j][6]) | (f2bf(acc[j][7]) << 16);
            *(uint4*)&hbf[(size_t)r * 64 + cg * 4] = pk;
            if ((cg & 3) == 0) {
                as_[r * 4 + hd] = ps;
                ad_[r * 4 + hd] = pd;
            }
        }
    }
}

// ---------------- aggregation: one wave per dst node, bf16 h rows ----------------
// Weight dedup: lanes compute each (edge,head) weight once (lane c=lane&31
// handles edge c>>2, head c&3), consumers fetch via __shfl. 8-way MLP unroll.
__global__ __launch_bounds__(256) void aggregate(const uint32_t* __restrict__ hb,
                                                 const float* __restrict__ as_,
                                                 const float* __restrict__ ad_,
                                                 const int* __restrict__ rowptr,
                                                 const int* __restrict__ colidx,
                                                 const float* __restrict__ bias,
                                                 float* __restrict__ out, int n, int do_elu) {
    int node = blockIdx.x * 4 + (threadIdx.x >> 6);
    if (node >= n) return;
    int lane = threadIdx.x & 63;
    int hd = lane >> 4;          // head of this lane's 2 output columns
    int k = lane * 2;
    int c = lane & 31;           // computing-lane id
    int ce = c >> 2;             // edge-in-batch this lane computes
    int ch = c & 3;              // head this lane computes
    float adn = ad_[node * 4 + hd];
    float adc = ad_[node * 4 + ch];
    float accx = 0.f, accy = 0.f, denom = 0.f;

    {   // self loop
        float wgt = __expf(lrelu(as_[node * 4 + hd] + adn));
        uint32_t u = hb[(size_t)node * 64 + lane];
        accx = fmaf(wgt, __uint_as_float(u << 16), accx);
        accy = fmaf(wgt, __uint_as_float(u & 0xFFFF0000u), accy);
        denom += wgt;
    }
    const int beg = rowptr[node], end = rowptr[node + 1];
    int j = beg;
    for (; j + 8 <= end; j += 8) {
        int s0 = colidx[j],     s1 = colidx[j + 1];
        int s2 = colidx[j + 2], s3 = colidx[j + 3];
        int s4 = colidx[j + 4], s5 = colidx[j + 5];
        int s6 = colidx[j + 6], s7 = colidx[j + 7];
        int sw = colidx[j + ce];                       // edge this lane weighs
        float aw = as_[sw * 4 + ch];
        uint32_t u0 = hb[(size_t)s0 * 64 + lane], u1 = hb[(size_t)s1 * 64 + lane];
        uint32_t u2 = hb[(size_t)s2 * 64 + lane], u3 = hb[(size_t)s3 * 64 + lane];
        uint32_t u4 = hb[(size_t)s4 * 64 + lane], u5 = hb[(size_t)s5 * 64 + lane];
        uint32_t u6 = hb[(size_t)s6 * 64 + lane], u7 = hb[(size_t)s7 * 64 + lane];
        float w = __expf(lrelu(aw + adc));
        float w0 = __shfl(w, 0  + hd), w1 = __shfl(w, 4  + hd);
        float w2 = __shfl(w, 8  + hd), w3 = __shfl(w, 12 + hd);
        float w4 = __shfl(w, 16 + hd), w5 = __shfl(w, 20 + hd);
        float w6 = __shfl(w, 24 + hd), w7 = __shfl(w, 28 + hd);
        accx = fmaf(w0, __uint_as_float(u0 << 16), accx);
        accy = fmaf(w0, __uint_as_float(u0 & 0xFFFF0000u), accy);
        accx = fmaf(w1, __uint_as_float(u1 << 16), accx);
        accy = fmaf(w1, __uint_as_float(u1 & 0xFFFF0000u), accy);
        accx = fmaf(w2, __uint_as_float(u2 << 16), accx);
        accy = fmaf(w2, __uint_as_float(u2 & 0xFFFF0000u), accy);
        accx = fmaf(w3, __uint_as_float(u3 << 16), accx);
        accy = fmaf(w3, __uint_as_float(u3 & 0xFFFF0000u), accy);
        accx = fmaf(w4, __uint_as_float(u4 << 16), accx);
        accy = fmaf(w4, __uint_as_float(u4 & 0xFFFF0000u), accy);
        accx = fmaf(w5, __uint_as_float(u5 << 16), accx);
        accy = fmaf(w5, __uint_as_float(u5 & 0xFFFF0000u), accy);
        accx = fmaf(w6, __uint_as_float(u6 << 16), accx);
        accy = fmaf(w6, __uint_as_float(u6 & 0xFFFF0000u), accy);
        accx = fmaf(w7, __uint_as_float(u7 << 16), accx);
        accy = fmaf(w7, __uint_as_float(u7 & 0xFFFF0000u), accy);
        denom += ((w0 + w1) + (w2 + w3)) + ((w4 + w5) + (w6 + w7));
    }
    for (; j < end; ++j) {
        int src = colidx[j];
        float wgt = __expf(lrelu(as_[src * 4 + hd] + adn));
        uint32_t u = hb[(size_t)src * 64 + lane];
        accx = fmaf(wgt, __uint_as_float(u << 16), accx);
        accy = fmaf(wgt, __uint_as_float(u & 0xFFFF0000u), accy);
        denom += wgt;
    }
    float inv = 1.f / (denom + 1e-16f);
    float o0 = fmaf(accx, inv, bias[k]);
    float o1 = fmaf(accy, inv, bias[k + 1]);
    if (do_elu) {
        o0 = o0 > 0.f ? o0 : (__expf(o0) - 1.f);
        o1 = o1 > 0.f ? o1 : (__expf(o1) - 1.f);
    }
    *(float2*)&out[(size_t)node * 128 + k] = make_float2(o0, o1);
}

extern "C" void kernel_launch(void* const* d_in, const int* in_sizes, int n_in,
                              void* d_out, int out_size, void* d_ws, size_t ws_size,
                              hipStream_t stream) {
    const float* x   = (const float*)d_in[0];
    const int*   ei  = (const int*)d_in[1];
    const float* W1  = (const float*)d_in[2];
    const float* a1s = (const float*)d_in[3];
    const float* a1d = (const float*)d_in[4];
    const float* b1  = (const float*)d_in[5];
    const float* W2  = (const float*)d_in[6];
    const float* a2s = (const float*)d_in[7];
    const float* a2d = (const float*)d_in[8];
    const float* b2  = (const float*)d_in[9];
    float* out = (float*)d_out;

    const int N = in_sizes[0] / 128;
    const int E = in_sizes[1] / 2;
    const int* esrc = ei;
    const int* edst = ei + E;

    char* w = (char*)d_ws;
    uint32_t* hbf  = (uint32_t*)w; w += (size_t)N * 64 * 4;   // bf16-packed h
    float*    as_  = (float*)w;    w += (size_t)N * 4 * 4;
    float*    ad_  = (float*)w;    w += (size_t)N * 4 * 4;
    int* deg    = (int*)w;   w += (size_t)N * 4;
    int* rowptr = (int*)w;   w += (size_t)(N + 1) * 4;
    int* rank   = (int*)w;   w += (size_t)E * 4;
    int* colidx = (int*)w;   w += (size_t)E * 4;
    int* csum   = (int*)w;   w += 256 * 4;
    int* coff   = (int*)w;   w += 256 * 4;
    float* out1 = out;   // layer-1 output lives in d_out; consumed by layer-2
                         // gemm before the final aggregate overwrites d_out

    hipMemsetAsync(deg, 0, (size_t)N * 4, stream);

    const int eb = (E + 255) / 256;
    const int ntot = N + 1;
    const int nch = (ntot + 255) / 256;

    count_rank<<<eb, 256, 0, stream>>>(edst, E, deg, rank);
    scan1<<<nch, 256, 0, stream>>>(deg, N, ntot, rowptr, csum);
    scan2<<<1, 256, 0, stream>>>(csum, coff, nch);
    scan3<<<nch, 256, 0, stream>>>(rowptr, coff, ntot);
    fill_csr<<<eb, 256, 0, stream>>>(esrc, edst, rank, E, rowptr, colidx);

    const int gb = (N + 127) / 128;
    const int nb = (N + 3) / 4;

    // layer 1
    gemm_alpha<<<gb, 256, 0, stream>>>(x, W1, a1s, a1d, hbf, as_, ad_, N);
    aggregate<<<nb, 256, 0, stream>>>(hbf, as_, ad_, rowptr, colidx, b1, out1, N, 1);

    // layer 2
    gemm_alpha<<<gb, 256, 0, stream>>>(out1, W2, a2s, a2d, hbf, as_, ad_, N);
    aggregate<<<nb, 256, 0, stream>>>(hbf, as_, ad_, rowptr, colidx, b2, out, N, 0);
}